// Round 2
// baseline (811.106 us; speedup 1.0000x reference)
//
#include <hip/hip_runtime.h>
#include <hip/hip_bf16.h>

#define NQ 4096
#define EMBED 256
#define HEADS 8
#define HEAD_DIM 32
#define LEVELS 4
#define POINTS 8
#define CAMS 6
#define LTOT 19560
#define MROWS (CAMS * LTOT)   // 117360

// ---------------------------------------------------------------------------
// Detect bev_mask element size. Scan first 98304 bytes (safe under both the
// uint8-bool and int32 layouts). If any byte at a non-word-aligned offset is
// nonzero -> uint8 layout (flag=1). If the data were int32 0/1 values, all
// such bytes are zero.
// ---------------------------------------------------------------------------
__global__ __launch_bounds__(256) void detect_kernel(const unsigned int* __restrict__ bm,
                                                     unsigned int* __restrict__ flag) {
    __shared__ unsigned int red[256];
    const int t = threadIdx.x;
    unsigned int acc = 0;
    for (int i = t; i < (CAMS * NQ * 4) / 4; i += 256)   // 24576 words
        acc |= (bm[i] & 0xFFFFFF00u);
    red[t] = acc;
    __syncthreads();
    for (int s = 128; s > 0; s >>= 1) {
        if (t < s) red[t] |= red[t + s];
        __syncthreads();
    }
    if (t == 0) flag[0] = red[0] ? 1u : 0u;
}

// ---------------------------------------------------------------------------
// maskf[c][q] = any(bev_mask[c,0,q,:]) ? 1 : 0 ; countf[q] = max(sum_c, 1)
// ---------------------------------------------------------------------------
__global__ __launch_bounds__(256) void mask_kernel(const void* __restrict__ bm,
                                                   const unsigned int* __restrict__ flag,
                                                   float* __restrict__ maskf,
                                                   float* __restrict__ countf) {
    const int q = blockIdx.x * 256 + threadIdx.x;
    if (q >= NQ) return;
    const bool u8 = (flag[0] != 0);
    float cnt = 0.f;
    #pragma unroll
    for (int c = 0; c < CAMS; c++) {
        bool hit;
        if (u8) {
            const unsigned int w = ((const unsigned int*)bm)[c * NQ + q];  // 4 packed bools
            hit = (w != 0);
        } else {
            const int* p = (const int*)bm;
            int s = 0;
            #pragma unroll
            for (int d = 0; d < 4; d++) s |= p[(c * NQ + q) * 4 + d];
            hit = (s != 0);
        }
        maskf[c * NQ + q] = hit ? 1.f : 0.f;
        cnt += hit ? 1.f : 0.f;
    }
    countf[q] = fmaxf(cnt, 1.f);
}

// ---------------------------------------------------------------------------
// Offset + attention projections (shared across cams) + softmax.
// 4 queries per block, 256 threads. Each thread: 2 off cols + 1 attn col.
// ---------------------------------------------------------------------------
__global__ __launch_bounds__(256) void proj_kernel(const float* __restrict__ query,
                                                   const float* __restrict__ W_off,
                                                   const float* __restrict__ b_off,
                                                   const float* __restrict__ W_attn,
                                                   const float* __restrict__ b_attn,
                                                   float* __restrict__ offn,
                                                   float* __restrict__ attnw) {
    const int t = threadIdx.x;
    const int q0 = blockIdx.x * 4;
    __shared__ float qs[4][EMBED];
    __shared__ float lat[4][EMBED];
    #pragma unroll
    for (int i = 0; i < 4; i++) qs[i][t] = query[(size_t)(q0 + i) * EMBED + t];
    __syncthreads();

    float aO0[4] = {0, 0, 0, 0}, aO1[4] = {0, 0, 0, 0}, aA[4] = {0, 0, 0, 0};
    #pragma unroll 4
    for (int k = 0; k < EMBED; k++) {
        const float w0 = W_off[k * 512 + t];
        const float w1 = W_off[k * 512 + 256 + t];
        const float wa = W_attn[k * 256 + t];
        #pragma unroll
        for (int i = 0; i < 4; i++) {
            const float qv = qs[i][k];
            aO0[i] += qv * w0;
            aO1[i] += qv * w1;
            aA[i]  += qv * wa;
        }
    }

    // normalize offsets: col j = h*64 + l*16 + p*2 + xy ; divide x by W_l, y by H_l
    const float Wl[4] = {160.f, 80.f, 40.f, 20.f};
    const float Hl[4] = {92.f, 46.f, 23.f, 12.f};
    const int j0 = t, j1 = t + 256;
    const int l0 = (j0 & 63) >> 4, l1 = (j1 & 63) >> 4;
    const float inv0 = 1.0f / ((j0 & 1) ? Hl[l0] : Wl[l0]);
    const float inv1 = 1.0f / ((j1 & 1) ? Hl[l1] : Wl[l1]);
    const float bo0 = b_off[j0], bo1 = b_off[j1], ba = b_attn[t];
    #pragma unroll
    for (int i = 0; i < 4; i++) {
        offn[(size_t)(q0 + i) * 512 + j0] = (aO0[i] + bo0) * inv0;
        offn[(size_t)(q0 + i) * 512 + j1] = (aO1[i] + bo1) * inv1;
        lat[i][t] = aA[i] + ba;
    }
    __syncthreads();

    // softmax over 32 (levels*points) per head
    const int h = t >> 5, lane = t & 31;
    #pragma unroll
    for (int i = 0; i < 4; i++) {
        const float v = lat[i][h * 32 + lane];
        float m = v;
        for (int s = 16; s > 0; s >>= 1) m = fmaxf(m, __shfl_xor(m, s, 32));
        const float e = expf(v - m);
        float ssum = e;
        for (int s = 16; s > 0; s >>= 1) ssum += __shfl_xor(ssum, s, 32);
        attnw[(size_t)(q0 + i) * 256 + h * 32 + lane] = e / ssum;
    }
}

// ---------------------------------------------------------------------------
// Value projection GEMM: val[m][n] = A[m][:] @ W[:,n] + bias[n]
// A: (117360, 256) f32, W: (256,256) row-major. 64x64 tile, BK=16, 4x4/thread.
// ---------------------------------------------------------------------------
#define BM 64
#define BN 64
#define BK 16
__global__ __launch_bounds__(256) void gemm_val(const float* __restrict__ A,
                                                const float* __restrict__ W,
                                                const float* __restrict__ bias,
                                                float* __restrict__ C, int M) {
    __shared__ float As[BK][BM + 1];
    __shared__ float Bs[BK][BN];
    const int t = threadIdx.x;
    const int m0 = blockIdx.x * BM, n0 = blockIdx.y * BN;
    const int tx = t & 15, ty = t >> 4;

    const int lm = t >> 2;         // 0..63: A row
    const int lk = (t & 3) * 4;    // A k offset (float4)
    const int bk = t >> 4;         // 0..15: W row
    const int bn = (t & 15) * 4;   // W col offset (float4)

    float acc[4][4] = {};
    for (int k0 = 0; k0 < EMBED; k0 += BK) {
        float4 av = make_float4(0, 0, 0, 0);
        const int gm = m0 + lm;
        if (gm < M) av = *(const float4*)&A[(size_t)gm * EMBED + k0 + lk];
        As[lk + 0][lm] = av.x;
        As[lk + 1][lm] = av.y;
        As[lk + 2][lm] = av.z;
        As[lk + 3][lm] = av.w;
        *(float4*)&Bs[bk][bn] = *(const float4*)&W[(size_t)(k0 + bk) * EMBED + n0 + bn];
        __syncthreads();
        #pragma unroll
        for (int kk = 0; kk < BK; kk++) {
            const float a0 = As[kk][ty * 4 + 0];
            const float a1 = As[kk][ty * 4 + 1];
            const float a2 = As[kk][ty * 4 + 2];
            const float a3 = As[kk][ty * 4 + 3];
            const float4 b4 = *(const float4*)&Bs[kk][tx * 4];
            acc[0][0] += a0 * b4.x; acc[0][1] += a0 * b4.y; acc[0][2] += a0 * b4.z; acc[0][3] += a0 * b4.w;
            acc[1][0] += a1 * b4.x; acc[1][1] += a1 * b4.y; acc[1][2] += a1 * b4.z; acc[1][3] += a1 * b4.w;
            acc[2][0] += a2 * b4.x; acc[2][1] += a2 * b4.y; acc[2][2] += a2 * b4.z; acc[2][3] += a2 * b4.w;
            acc[3][0] += a3 * b4.x; acc[3][1] += a3 * b4.y; acc[3][2] += a3 * b4.z; acc[3][3] += a3 * b4.w;
        }
        __syncthreads();
    }
    #pragma unroll
    for (int i = 0; i < 4; i++) {
        const int gm = m0 + ty * 4 + i;
        if (gm >= M) continue;
        #pragma unroll
        for (int j = 0; j < 4; j++) {
            const int gn = n0 + tx * 4 + j;
            C[(size_t)gm * EMBED + gn] = acc[i][j] + bias[gn];
        }
    }
}

// ---------------------------------------------------------------------------
// Deformable bilinear sampling. One block per (cam, q); 8 head-groups of 32
// lanes (lane = head_dim channel). Skips (cam,q) with mask miss.
// ---------------------------------------------------------------------------
__global__ __launch_bounds__(256) void sample_kernel(const float* __restrict__ refp,
                                                     const float* __restrict__ offn,
                                                     const float* __restrict__ attnw,
                                                     const float* __restrict__ val,
                                                     const float* __restrict__ maskf,
                                                     float* __restrict__ out_cam) {
    const int blk = blockIdx.x;
    const int cam = blk >> 12;
    const int q = blk & (NQ - 1);
    if (maskf[cam * NQ + q] == 0.f) return;   // combine kernel multiplies by 0

    const int h = threadIdx.x >> 5;
    const int d = threadIdx.x & 31;

    const float* refq = refp + ((size_t)cam * NQ + q) * 8;
    const float* offq = offn + (size_t)q * 512 + h * 64;
    const float* attq = attnw + (size_t)q * 256 + h * 32;
    const float* valc = val + (size_t)cam * LTOT * EMBED + h * HEAD_DIM + d;

    float rx[4], ry[4];
    #pragma unroll
    for (int i = 0; i < 4; i++) { rx[i] = refq[i * 2]; ry[i] = refq[i * 2 + 1]; }

    const int Hs[4] = {92, 46, 23, 12};
    const int Ws[4] = {160, 80, 40, 20};
    const int st[4] = {0, 14720, 18400, 19320};

    float acc = 0.f;
    #pragma unroll
    for (int l = 0; l < LEVELS; l++) {
        const int H = Hs[l], W = Ws[l];
        const float* vl = valc + (size_t)st[l] * EMBED;
        #pragma unroll
        for (int p = 0; p < POINTS; p++) {
            const float ox = offq[l * 16 + p * 2];
            const float oy = offq[l * 16 + p * 2 + 1];
            const float x = (rx[p & 3] + ox) * W - 0.5f;
            const float y = (ry[p & 3] + oy) * H - 0.5f;
            const float x0f = floorf(x), y0f = floorf(y);
            const float lx = x - x0f, ly = y - y0f;
            const int x0 = (int)x0f, y0 = (int)y0f;
            const int x1 = x0 + 1, y1 = y0 + 1;
            const float a = attq[l * 8 + p];
            const float w00 = (1.f - lx) * (1.f - ly) * a;
            const float w10 = lx * (1.f - ly) * a;
            const float w01 = (1.f - lx) * ly * a;
            const float w11 = lx * ly * a;
            const bool vx0 = (x0 >= 0) & (x0 < W), vx1 = (x1 >= 0) & (x1 < W);
            const bool vy0 = (y0 >= 0) & (y0 < H), vy1 = (y1 >= 0) & (y1 < H);
            if (vx0 & vy0) acc += w00 * vl[(size_t)(y0 * W + x0) * EMBED];
            if (vx1 & vy0) acc += w10 * vl[(size_t)(y0 * W + x1) * EMBED];
            if (vx0 & vy1) acc += w01 * vl[(size_t)(y1 * W + x0) * EMBED];
            if (vx1 & vy1) acc += w11 * vl[(size_t)(y1 * W + x1) * EMBED];
        }
    }
    out_cam[((size_t)cam * NQ + q) * EMBED + h * HEAD_DIM + d] = acc;
}

// ---------------------------------------------------------------------------
// Masked mean over cams + output projection + residual.
// ---------------------------------------------------------------------------
__global__ __launch_bounds__(256) void out_kernel(const float* __restrict__ out_cam,
                                                  const float* __restrict__ maskf,
                                                  const float* __restrict__ countf,
                                                  const float* __restrict__ W_out,
                                                  const float* __restrict__ b_out,
                                                  const float* __restrict__ query,
                                                  float* __restrict__ out) {
    const int q = blockIdx.x;
    const int t = threadIdx.x;
    __shared__ float s[EMBED];
    float acc = 0.f;
    #pragma unroll
    for (int c = 0; c < CAMS; c++)
        acc += maskf[c * NQ + q] * out_cam[(((size_t)c * NQ + q) << 8) + t];
    s[t] = acc / countf[q];
    __syncthreads();
    float o = b_out[t];
    #pragma unroll 4
    for (int k = 0; k < EMBED; k++) o += s[k] * W_out[k * EMBED + t];
    out[(size_t)q * EMBED + t] = o + query[(size_t)q * EMBED + t];
}

extern "C" void kernel_launch(void* const* d_in, const int* in_sizes, int n_in,
                              void* d_out, int out_size, void* d_ws, size_t ws_size,
                              hipStream_t stream) {
    const float* query      = (const float*)d_in[0];
    // d_in[1] = key_feat (unused by reference)
    const float* value_feat = (const float*)d_in[2];
    const float* refp       = (const float*)d_in[3];
    const void*  bev        = d_in[4];
    const float* W_value    = (const float*)d_in[7];
    const float* b_value    = (const float*)d_in[8];
    const float* W_off      = (const float*)d_in[9];
    const float* b_off      = (const float*)d_in[10];
    const float* W_attn     = (const float*)d_in[11];
    const float* b_attn     = (const float*)d_in[12];
    const float* W_out      = (const float*)d_in[13];
    const float* b_out      = (const float*)d_in[14];

    float* ws     = (float*)d_ws;
    float* offn   = ws;                          // 4096*512  = 2097152
    float* attnw  = offn + 2097152;              // 4096*256  = 1048576
    float* maskf  = attnw + 1048576;             // 6*4096    = 24576
    float* countf = maskf + 24576;               // 4096
    unsigned int* flag = (unsigned int*)(countf + 4096);
    float* val    = countf + 4096 + 64;          // 117360*256 = 30044160
    float* out_cam = val + (size_t)MROWS * EMBED; // 6*4096*256 = 6291456

    detect_kernel<<<1, 256, 0, stream>>>((const unsigned int*)bev, flag);
    mask_kernel<<<16, 256, 0, stream>>>(bev, flag, maskf, countf);
    proj_kernel<<<NQ / 4, 256, 0, stream>>>(query, W_off, b_off, W_attn, b_attn, offn, attnw);
    gemm_val<<<dim3((MROWS + BM - 1) / BM, EMBED / BN), 256, 0, stream>>>(
        value_feat, W_value, b_value, val, MROWS);
    sample_kernel<<<CAMS * NQ, 256, 0, stream>>>(refp, offn, attnw, val, maskf, out_cam);
    out_kernel<<<NQ, 256, 0, stream>>>(out_cam, maskf, countf, W_out, b_out, query, (float*)d_out);
}

// Round 3
// 418.430 us; speedup vs baseline: 1.9385x; 1.9385x over previous
//
#include <hip/hip_runtime.h>
#include <hip/hip_bf16.h>

#define NQ 4096
#define EMBED 256
#define HEADS 8
#define HEAD_DIM 32
#define LEVELS 4
#define POINTS 8
#define CAMS 6
#define LTOT 19560
#define MROWS (CAMS * LTOT)   // 117360

using bf16x8 = __attribute__((ext_vector_type(8))) __bf16;
using f32x4v = __attribute__((ext_vector_type(4))) float;

__device__ inline ushort f2bf(float f) {
    unsigned u = __builtin_bit_cast(unsigned, f);
    u += 0x7FFFu + ((u >> 16) & 1u);   // round-to-nearest-even
    return (ushort)(u >> 16);
}

// ---------------------------------------------------------------------------
// Detect bev_mask element size (uint8 bools vs int32). Any nonzero byte at a
// non-word-aligned offset -> uint8 layout.
// ---------------------------------------------------------------------------
__global__ __launch_bounds__(256) void detect_kernel(const unsigned int* __restrict__ bm,
                                                     unsigned int* __restrict__ flag) {
    __shared__ unsigned int red[256];
    const int t = threadIdx.x;
    unsigned int acc = 0;
    for (int i = t; i < (CAMS * NQ * 4) / 4; i += 256)
        acc |= (bm[i] & 0xFFFFFF00u);
    red[t] = acc;
    __syncthreads();
    for (int s = 128; s > 0; s >>= 1) {
        if (t < s) red[t] |= red[t + s];
        __syncthreads();
    }
    if (t == 0) flag[0] = red[0] ? 1u : 0u;
}

__global__ __launch_bounds__(256) void mask_kernel(const void* __restrict__ bm,
                                                   const unsigned int* __restrict__ flag,
                                                   float* __restrict__ maskf,
                                                   float* __restrict__ countf) {
    const int q = blockIdx.x * 256 + threadIdx.x;
    if (q >= NQ) return;
    const bool u8 = (flag[0] != 0);
    float cnt = 0.f;
    #pragma unroll
    for (int c = 0; c < CAMS; c++) {
        bool hit;
        if (u8) {
            const unsigned int w = ((const unsigned int*)bm)[c * NQ + q];
            hit = (w != 0);
        } else {
            const int* p = (const int*)bm;
            int s = 0;
            #pragma unroll
            for (int d = 0; d < 4; d++) s |= p[(c * NQ + q) * 4 + d];
            hit = (s != 0);
        }
        maskf[c * NQ + q] = hit ? 1.f : 0.f;
        cnt += hit ? 1.f : 0.f;
    }
    countf[q] = fmaxf(cnt, 1.f);
}

// ---------------------------------------------------------------------------
// Offset + attention projections + softmax (shared across cams).
// ---------------------------------------------------------------------------
__global__ __launch_bounds__(256) void proj_kernel(const float* __restrict__ query,
                                                   const float* __restrict__ W_off,
                                                   const float* __restrict__ b_off,
                                                   const float* __restrict__ W_attn,
                                                   const float* __restrict__ b_attn,
                                                   float* __restrict__ offn,
                                                   float* __restrict__ attnw) {
    const int t = threadIdx.x;
    const int q0 = blockIdx.x * 4;
    __shared__ float qs[4][EMBED];
    __shared__ float lat[4][EMBED];
    #pragma unroll
    for (int i = 0; i < 4; i++) qs[i][t] = query[(size_t)(q0 + i) * EMBED + t];
    __syncthreads();

    float aO0[4] = {0, 0, 0, 0}, aO1[4] = {0, 0, 0, 0}, aA[4] = {0, 0, 0, 0};
    #pragma unroll 4
    for (int k = 0; k < EMBED; k++) {
        const float w0 = W_off[k * 512 + t];
        const float w1 = W_off[k * 512 + 256 + t];
        const float wa = W_attn[k * 256 + t];
        #pragma unroll
        for (int i = 0; i < 4; i++) {
            const float qv = qs[i][k];
            aO0[i] += qv * w0;
            aO1[i] += qv * w1;
            aA[i]  += qv * wa;
        }
    }

    const float Wl[4] = {160.f, 80.f, 40.f, 20.f};
    const float Hl[4] = {92.f, 46.f, 23.f, 12.f};
    const int j0 = t, j1 = t + 256;
    const int l0 = (j0 & 63) >> 4, l1 = (j1 & 63) >> 4;
    const float inv0 = 1.0f / ((j0 & 1) ? Hl[l0] : Wl[l0]);
    const float inv1 = 1.0f / ((j1 & 1) ? Hl[l1] : Wl[l1]);
    const float bo0 = b_off[j0], bo1 = b_off[j1], ba = b_attn[t];
    #pragma unroll
    for (int i = 0; i < 4; i++) {
        offn[(size_t)(q0 + i) * 512 + j0] = (aO0[i] + bo0) * inv0;
        offn[(size_t)(q0 + i) * 512 + j1] = (aO1[i] + bo1) * inv1;
        lat[i][t] = aA[i] + ba;
    }
    __syncthreads();

    const int h = t >> 5, lane = t & 31;
    #pragma unroll
    for (int i = 0; i < 4; i++) {
        const float v = lat[i][h * 32 + lane];
        float m = v;
        for (int s = 16; s > 0; s >>= 1) m = fmaxf(m, __shfl_xor(m, s, 32));
        const float e = expf(v - m);
        float ssum = e;
        for (int s = 16; s > 0; s >>= 1) ssum += __shfl_xor(ssum, s, 32);
        attnw[(size_t)(q0 + i) * 256 + h * 32 + lane] = e / ssum;
    }
}

// ---------------------------------------------------------------------------
// W_value -> WT bf16 transposed [n][k] (one-time, tiny).
// ---------------------------------------------------------------------------
__global__ __launch_bounds__(256) void wt_kernel(const float* __restrict__ W,
                                                 ushort* __restrict__ WT) {
    __shared__ float tile[32][33];
    const int b = blockIdx.x;            // 64 blocks: 8x8 tiles of 32x32
    const int kt = b >> 3, nt = b & 7;
    const int t = threadIdx.x;
    const int r = t >> 5, c = t & 31;
    #pragma unroll
    for (int it = 0; it < 4; it++)
        tile[it * 8 + r][c] = W[(size_t)(kt * 32 + it * 8 + r) * 256 + nt * 32 + c];
    __syncthreads();
    #pragma unroll
    for (int it = 0; it < 4; it++)
        WT[(size_t)(nt * 32 + it * 8 + r) * 256 + kt * 32 + c] = f2bf(tile[c][it * 8 + r]);
}

// ---------------------------------------------------------------------------
// Value projection: bf16 MFMA GEMM. C[m][n] = A[m][:] @ W[:,n] + bias[n].
// 128x128 tile, BK=32, 4 waves (2x2 of 64x64). Fused f32->bf16 staging.
// Frag layout (16x16x32_bf16): A: lane l -> A[row=l&15][k=(l>>4)*8+j];
// B: lane l -> B[k=(l>>4)*8+j][col=l&15]; D: [row=(l>>4)*4+r][col=l&15].
// ---------------------------------------------------------------------------
#define GBM 128
#define GBN 128
#define GBK 32
#define LDT 40   // padded LDS stride (bf16): 80 B, 16B-aligned, ~2-way banks

__global__ __launch_bounds__(256) void gemm_mfma(const float* __restrict__ A,
                                                 const ushort* __restrict__ WT,
                                                 const float* __restrict__ bias,
                                                 float* __restrict__ C, int M) {
    __shared__ ushort As[GBM * LDT];
    __shared__ ushort Bs[GBN * LDT];
    const int t = threadIdx.x;
    const int wave = t >> 6, lane = t & 63;
    const int wm = (wave & 1) * 64, wn = (wave >> 1) * 64;
    const int m0 = blockIdx.x * GBM, n0 = blockIdx.y * GBN;
    const int fl = lane & 15, fk = (lane >> 4) * 8;
    const int sr = t >> 1, sk = (t & 1) * 16;

    int ar = m0 + sr; if (ar >= M) ar = M - 1;
    const float*  arow = A  + (size_t)ar * 256;
    const ushort* brow = WT + (size_t)(n0 + sr) * 256;

    f32x4v acc[4][4];
    #pragma unroll
    for (int i = 0; i < 4; i++)
        #pragma unroll
        for (int j = 0; j < 4; j++) acc[i][j] = (f32x4v)(0.f);

    for (int k0 = 0; k0 < 256; k0 += GBK) {
        unsigned w[8];
        #pragma unroll
        for (int u = 0; u < 8; u++) {
            const float2 v = *(const float2*)&arow[k0 + sk + u * 2];
            w[u] = (unsigned)f2bf(v.x) | ((unsigned)f2bf(v.y) << 16);
        }
        *(uint4*)&As[sr * LDT + sk]     = make_uint4(w[0], w[1], w[2], w[3]);
        *(uint4*)&As[sr * LDT + sk + 8] = make_uint4(w[4], w[5], w[6], w[7]);
        const uint4* bp = (const uint4*)&brow[k0 + sk];
        *(uint4*)&Bs[sr * LDT + sk]     = bp[0];
        *(uint4*)&Bs[sr * LDT + sk + 8] = bp[1];
        __syncthreads();

        bf16x8 af[4], bfv[4];
        #pragma unroll
        for (int i = 0; i < 4; i++)
            af[i] = *(const bf16x8*)&As[(wm + i * 16 + fl) * LDT + fk];
        #pragma unroll
        for (int j = 0; j < 4; j++)
            bfv[j] = *(const bf16x8*)&Bs[(wn + j * 16 + fl) * LDT + fk];
        #pragma unroll
        for (int i = 0; i < 4; i++)
            #pragma unroll
            for (int j = 0; j < 4; j++)
                acc[i][j] = __builtin_amdgcn_mfma_f32_16x16x32_bf16(af[i], bfv[j], acc[i][j], 0, 0, 0);
        __syncthreads();
    }

    const int rb = (lane >> 4) * 4;
    #pragma unroll
    for (int j = 0; j < 4; j++) {
        const int col = n0 + wn + j * 16 + fl;
        const float bv = bias[col];
        #pragma unroll
        for (int i = 0; i < 4; i++) {
            #pragma unroll
            for (int r = 0; r < 4; r++) {
                const int row = m0 + wm + i * 16 + rb + r;
                if (row < M) C[(size_t)row * 256 + col] = acc[i][j][r] + bv;
            }
        }
    }
}

// ---------------------------------------------------------------------------
// Deformable bilinear sampling. One WAVE per (cam,q): 8 heads x 8 lanes,
// each lane owns 4 channels (float4 gathers). 4 pairs per block.
// ---------------------------------------------------------------------------
__global__ __launch_bounds__(256) void sample_kernel(const float* __restrict__ refp,
                                                     const float* __restrict__ offn,
                                                     const float* __restrict__ attnw,
                                                     const float* __restrict__ val,
                                                     const float* __restrict__ maskf,
                                                     float* __restrict__ out_cam) {
    const int wv = threadIdx.x >> 6, lane = threadIdx.x & 63;
    const int pair = blockIdx.x * 4 + wv;
    const int cam = pair >> 12, q = pair & (NQ - 1);
    if (maskf[cam * NQ + q] == 0.f) return;   // wave-uniform exit, no barriers

    const int h = lane >> 3, dg = lane & 7;
    const float* refq = refp + ((size_t)cam * NQ + q) * 8;
    const float* offq = offn + (size_t)q * 512 + h * 64;
    const float* attq = attnw + (size_t)q * 256 + h * 32;
    const float* valc = val + (size_t)cam * LTOT * EMBED + h * HEAD_DIM + dg * 4;

    float rx[4], ry[4];
    #pragma unroll
    for (int i = 0; i < 4; i++) { rx[i] = refq[2 * i]; ry[i] = refq[2 * i + 1]; }

    const int Hs[4] = {92, 46, 23, 12};
    const int Ws[4] = {160, 80, 40, 20};
    const int st[4] = {0, 14720, 18400, 19320};

    float a0 = 0.f, a1 = 0.f, a2 = 0.f, a3 = 0.f;
    #pragma unroll
    for (int l = 0; l < LEVELS; l++) {
        const int H = Hs[l], W = Ws[l];
        const float fW = (float)W, fH = (float)H;
        const float* vl = valc + (size_t)st[l] * EMBED;
        #pragma unroll
        for (int p = 0; p < POINTS; p++) {
            const float x = (rx[p & 3] + offq[l * 16 + p * 2]) * fW - 0.5f;
            const float y = (ry[p & 3] + offq[l * 16 + p * 2 + 1]) * fH - 0.5f;
            const float x0f = floorf(x), y0f = floorf(y);
            const float lx = x - x0f, ly = y - y0f;
            const int x0 = (int)x0f, y0 = (int)y0f, x1 = x0 + 1, y1 = y0 + 1;
            const float aw = attq[l * 8 + p];
            const float w00 = (1.f - lx) * (1.f - ly) * aw;
            const float w10 = lx * (1.f - ly) * aw;
            const float w01 = (1.f - lx) * ly * aw;
            const float w11 = lx * ly * aw;
            const bool vx0 = (x0 >= 0) & (x0 < W), vx1 = (x1 >= 0) & (x1 < W);
            const bool vy0 = (y0 >= 0) & (y0 < H), vy1 = (y1 >= 0) & (y1 < H);
            if (vx0 & vy0) { const float4 v = *(const float4*)&vl[(size_t)(y0 * W + x0) * EMBED];
                a0 += w00 * v.x; a1 += w00 * v.y; a2 += w00 * v.z; a3 += w00 * v.w; }
            if (vx1 & vy0) { const float4 v = *(const float4*)&vl[(size_t)(y0 * W + x1) * EMBED];
                a0 += w10 * v.x; a1 += w10 * v.y; a2 += w10 * v.z; a3 += w10 * v.w; }
            if (vx0 & vy1) { const float4 v = *(const float4*)&vl[(size_t)(y1 * W + x0) * EMBED];
                a0 += w01 * v.x; a1 += w01 * v.y; a2 += w01 * v.z; a3 += w01 * v.w; }
            if (vx1 & vy1) { const float4 v = *(const float4*)&vl[(size_t)(y1 * W + x1) * EMBED];
                a0 += w11 * v.x; a1 += w11 * v.y; a2 += w11 * v.z; a3 += w11 * v.w; }
        }
    }
    float4 o; o.x = a0; o.y = a1; o.z = a2; o.w = a3;
    *(float4*)&out_cam[((size_t)cam * NQ + q) * EMBED + h * HEAD_DIM + dg * 4] = o;
}

// ---------------------------------------------------------------------------
// Masked mean over cams + output projection + residual.
// ---------------------------------------------------------------------------
__global__ __launch_bounds__(256) void out_kernel(const float* __restrict__ out_cam,
                                                  const float* __restrict__ maskf,
                                                  const float* __restrict__ countf,
                                                  const float* __restrict__ W_out,
                                                  const float* __restrict__ b_out,
                                                  const float* __restrict__ query,
                                                  float* __restrict__ out) {
    const int q = blockIdx.x;
    const int t = threadIdx.x;
    __shared__ float s[EMBED];
    float acc = 0.f;
    #pragma unroll
    for (int c = 0; c < CAMS; c++)
        acc += maskf[c * NQ + q] * out_cam[(((size_t)c * NQ + q) << 8) + t];
    s[t] = acc / countf[q];
    __syncthreads();
    float o = b_out[t];
    #pragma unroll 4
    for (int k = 0; k < EMBED; k++) o += s[k] * W_out[k * EMBED + t];
    out[(size_t)q * EMBED + t] = o + query[(size_t)q * EMBED + t];
}

extern "C" void kernel_launch(void* const* d_in, const int* in_sizes, int n_in,
                              void* d_out, int out_size, void* d_ws, size_t ws_size,
                              hipStream_t stream) {
    const float* query      = (const float*)d_in[0];
    const float* value_feat = (const float*)d_in[2];
    const float* refp       = (const float*)d_in[3];
    const void*  bev        = d_in[4];
    const float* W_value    = (const float*)d_in[7];
    const float* b_value    = (const float*)d_in[8];
    const float* W_off      = (const float*)d_in[9];
    const float* b_off      = (const float*)d_in[10];
    const float* W_attn     = (const float*)d_in[11];
    const float* b_attn     = (const float*)d_in[12];
    const float* W_out      = (const float*)d_in[13];
    const float* b_out      = (const float*)d_in[14];

    float* ws      = (float*)d_ws;
    float* offn    = ws;                             // 4096*512
    float* attnw   = offn + 2097152;                 // 4096*256
    float* maskf   = attnw + 1048576;                // 6*4096
    float* countf  = maskf + 24576;                  // 4096
    unsigned int* flag = (unsigned int*)(countf + 4096);
    float* val     = countf + 4096 + 64;             // 117360*256
    float* out_cam = val + (size_t)MROWS * EMBED;    // 6*4096*256
    const size_t used_floats = 39510080;             // end of out_cam
    ushort* WT = (ushort*)(ws + used_floats);        // 256*256 bf16 = 128 KB
    if (ws_size < used_floats * 4 + 131072)
        WT = (ushort*)out_cam;   // stream-serialized reuse; masked slots ×0 later

    detect_kernel<<<1, 256, 0, stream>>>((const unsigned int*)bev, flag);
    mask_kernel<<<16, 256, 0, stream>>>(bev, flag, maskf, countf);
    proj_kernel<<<NQ / 4, 256, 0, stream>>>(query, W_off, b_off, W_attn, b_attn, offn, attnw);
    wt_kernel<<<64, 256, 0, stream>>>(W_value, WT);
    gemm_mfma<<<dim3((MROWS + GBM - 1) / GBM, EMBED / GBN), 256, 0, stream>>>(
        value_feat, WT, b_value, val, MROWS);
    sample_kernel<<<CAMS * NQ / 4, 256, 0, stream>>>(refp, offn, attnw, val, maskf, out_cam);
    out_kernel<<<NQ, 256, 0, stream>>>(out_cam, maskf, countf, W_out, b_out, query, (float*)d_out);
}

// Round 4
// 338.030 us; speedup vs baseline: 2.3995x; 1.2378x over previous
//
#include <hip/hip_runtime.h>
#include <hip/hip_bf16.h>

#define NQ 4096
#define EMBED 256
#define HEADS 8
#define HEAD_DIM 32
#define LEVELS 4
#define POINTS 8
#define CAMS 6
#define LTOT 19560
#define MROWS (CAMS * LTOT)   // 117360

using bf16x8 = __attribute__((ext_vector_type(8))) __bf16;
using f32x4v = __attribute__((ext_vector_type(4))) float;

__device__ inline ushort f2bf(float f) {
    unsigned u = __builtin_bit_cast(unsigned, f);
    u += 0x7FFFu + ((u >> 16) & 1u);   // round-to-nearest-even
    return (ushort)(u >> 16);
}
__device__ inline float bf2f(ushort u) {
    return __builtin_bit_cast(float, ((unsigned)u) << 16);
}

// ---------------------------------------------------------------------------
// Detect bev_mask element size (uint8 bools vs int32).
// ---------------------------------------------------------------------------
__global__ __launch_bounds__(256) void detect_kernel(const unsigned int* __restrict__ bm,
                                                     unsigned int* __restrict__ flag) {
    __shared__ unsigned int red[256];
    const int t = threadIdx.x;
    unsigned int acc = 0;
    for (int i = t; i < (CAMS * NQ * 4) / 4; i += 256)
        acc |= (bm[i] & 0xFFFFFF00u);
    red[t] = acc;
    __syncthreads();
    for (int s = 128; s > 0; s >>= 1) {
        if (t < s) red[t] |= red[t + s];
        __syncthreads();
    }
    if (t == 0) flag[0] = red[0] ? 1u : 0u;
}

__global__ __launch_bounds__(256) void mask_kernel(const void* __restrict__ bm,
                                                   const unsigned int* __restrict__ flag,
                                                   float* __restrict__ maskf,
                                                   float* __restrict__ countf) {
    const int q = blockIdx.x * 256 + threadIdx.x;
    if (q >= NQ) return;
    const bool u8 = (flag[0] != 0);
    float cnt = 0.f;
    #pragma unroll
    for (int c = 0; c < CAMS; c++) {
        bool hit;
        if (u8) {
            const unsigned int w = ((const unsigned int*)bm)[c * NQ + q];
            hit = (w != 0);
        } else {
            const int* p = (const int*)bm;
            int s = 0;
            #pragma unroll
            for (int d = 0; d < 4; d++) s |= p[(c * NQ + q) * 4 + d];
            hit = (s != 0);
        }
        maskf[c * NQ + q] = hit ? 1.f : 0.f;
        cnt += hit ? 1.f : 0.f;
    }
    countf[q] = fmaxf(cnt, 1.f);
}

// ---------------------------------------------------------------------------
// Offset + attention projections + softmax (shared across cams).
// ---------------------------------------------------------------------------
__global__ __launch_bounds__(256) void proj_kernel(const float* __restrict__ query,
                                                   const float* __restrict__ W_off,
                                                   const float* __restrict__ b_off,
                                                   const float* __restrict__ W_attn,
                                                   const float* __restrict__ b_attn,
                                                   float* __restrict__ offn,
                                                   float* __restrict__ attnw) {
    const int t = threadIdx.x;
    const int q0 = blockIdx.x * 4;
    __shared__ float qs[4][EMBED];
    __shared__ float lat[4][EMBED];
    #pragma unroll
    for (int i = 0; i < 4; i++) qs[i][t] = query[(size_t)(q0 + i) * EMBED + t];
    __syncthreads();

    float aO0[4] = {0, 0, 0, 0}, aO1[4] = {0, 0, 0, 0}, aA[4] = {0, 0, 0, 0};
    #pragma unroll 4
    for (int k = 0; k < EMBED; k++) {
        const float w0 = W_off[k * 512 + t];
        const float w1 = W_off[k * 512 + 256 + t];
        const float wa = W_attn[k * 256 + t];
        #pragma unroll
        for (int i = 0; i < 4; i++) {
            const float qv = qs[i][k];
            aO0[i] += qv * w0;
            aO1[i] += qv * w1;
            aA[i]  += qv * wa;
        }
    }

    const float Wl[4] = {160.f, 80.f, 40.f, 20.f};
    const float Hl[4] = {92.f, 46.f, 23.f, 12.f};
    const int j0 = t, j1 = t + 256;
    const int l0 = (j0 & 63) >> 4, l1 = (j1 & 63) >> 4;
    const float inv0 = 1.0f / ((j0 & 1) ? Hl[l0] : Wl[l0]);
    const float inv1 = 1.0f / ((j1 & 1) ? Hl[l1] : Wl[l1]);
    const float bo0 = b_off[j0], bo1 = b_off[j1], ba = b_attn[t];
    #pragma unroll
    for (int i = 0; i < 4; i++) {
        offn[(size_t)(q0 + i) * 512 + j0] = (aO0[i] + bo0) * inv0;
        offn[(size_t)(q0 + i) * 512 + j1] = (aO1[i] + bo1) * inv1;
        lat[i][t] = aA[i] + ba;
    }
    __syncthreads();

    const int h = t >> 5, lane = t & 31;
    #pragma unroll
    for (int i = 0; i < 4; i++) {
        const float v = lat[i][h * 32 + lane];
        float m = v;
        for (int s = 16; s > 0; s >>= 1) m = fmaxf(m, __shfl_xor(m, s, 32));
        const float e = expf(v - m);
        float ssum = e;
        for (int s = 16; s > 0; s >>= 1) ssum += __shfl_xor(ssum, s, 32);
        attnw[(size_t)(q0 + i) * 256 + h * 32 + lane] = e / ssum;
    }
}

// ---------------------------------------------------------------------------
// W_value -> WT bf16 transposed [n][k] (one-time, tiny).
// ---------------------------------------------------------------------------
__global__ __launch_bounds__(256) void wt_kernel(const float* __restrict__ W,
                                                 ushort* __restrict__ WT) {
    __shared__ float tile[32][33];
    const int b = blockIdx.x;            // 64 blocks: 8x8 tiles of 32x32
    const int kt = b >> 3, nt = b & 7;
    const int t = threadIdx.x;
    const int r = t >> 5, c = t & 31;
    #pragma unroll
    for (int it = 0; it < 4; it++)
        tile[it * 8 + r][c] = W[(size_t)(kt * 32 + it * 8 + r) * 256 + nt * 32 + c];
    __syncthreads();
    #pragma unroll
    for (int it = 0; it < 4; it++)
        WT[(size_t)(nt * 32 + it * 8 + r) * 256 + kt * 32 + c] = f2bf(tile[c][it * 8 + r]);
}

// ---------------------------------------------------------------------------
// Value projection: bf16 MFMA GEMM, writes val in BF16.
// 128x128 tile, BK=32, 4 waves (2x2 of 64x64). Native (__bf16) casts in
// staging -> v_cvt_pk codegen.
// ---------------------------------------------------------------------------
#define GBM 128
#define GBN 128
#define GBK 32
#define LDT 40   // padded LDS stride (bf16): 80 B, 16B-aligned, ~2-way banks

__global__ __launch_bounds__(256) void gemm_mfma(const float* __restrict__ A,
                                                 const ushort* __restrict__ WT,
                                                 const float* __restrict__ bias,
                                                 ushort* __restrict__ C, int M) {
    __shared__ ushort As[GBM * LDT];
    __shared__ ushort Bs[GBN * LDT];
    const int t = threadIdx.x;
    const int wave = t >> 6, lane = t & 63;
    const int wm = (wave & 1) * 64, wn = (wave >> 1) * 64;
    const int m0 = blockIdx.x * GBM, n0 = blockIdx.y * GBN;
    const int fl = lane & 15, fk = (lane >> 4) * 8;
    const int sr = t >> 1, sk = (t & 1) * 16;

    int ar = m0 + sr; if (ar >= M) ar = M - 1;
    const float*  arow = A  + (size_t)ar * 256;
    const ushort* brow = WT + (size_t)(n0 + sr) * 256;

    f32x4v acc[4][4];
    #pragma unroll
    for (int i = 0; i < 4; i++)
        #pragma unroll
        for (int j = 0; j < 4; j++) acc[i][j] = (f32x4v)(0.f);

    for (int k0 = 0; k0 < 256; k0 += GBK) {
        bf16x8 w0, w1;
        #pragma unroll
        for (int u = 0; u < 2; u++) {
            const float4 v = *(const float4*)&arow[k0 + sk + u * 4];
            w0[u * 4 + 0] = (__bf16)v.x; w0[u * 4 + 1] = (__bf16)v.y;
            w0[u * 4 + 2] = (__bf16)v.z; w0[u * 4 + 3] = (__bf16)v.w;
        }
        #pragma unroll
        for (int u = 0; u < 2; u++) {
            const float4 v = *(const float4*)&arow[k0 + sk + 8 + u * 4];
            w1[u * 4 + 0] = (__bf16)v.x; w1[u * 4 + 1] = (__bf16)v.y;
            w1[u * 4 + 2] = (__bf16)v.z; w1[u * 4 + 3] = (__bf16)v.w;
        }
        *(bf16x8*)&As[sr * LDT + sk]     = w0;
        *(bf16x8*)&As[sr * LDT + sk + 8] = w1;
        const uint4* bp = (const uint4*)&brow[k0 + sk];
        *(uint4*)&Bs[sr * LDT + sk]     = bp[0];
        *(uint4*)&Bs[sr * LDT + sk + 8] = bp[1];
        __syncthreads();

        bf16x8 af[4], bfv[4];
        #pragma unroll
        for (int i = 0; i < 4; i++)
            af[i] = *(const bf16x8*)&As[(wm + i * 16 + fl) * LDT + fk];
        #pragma unroll
        for (int j = 0; j < 4; j++)
            bfv[j] = *(const bf16x8*)&Bs[(wn + j * 16 + fl) * LDT + fk];
        #pragma unroll
        for (int i = 0; i < 4; i++)
            #pragma unroll
            for (int j = 0; j < 4; j++)
                acc[i][j] = __builtin_amdgcn_mfma_f32_16x16x32_bf16(af[i], bfv[j], acc[i][j], 0, 0, 0);
        __syncthreads();
    }

    const int rb = (lane >> 4) * 4;
    #pragma unroll
    for (int j = 0; j < 4; j++) {
        const int col = n0 + wn + j * 16 + fl;
        const float bv = bias[col];
        #pragma unroll
        for (int i = 0; i < 4; i++) {
            #pragma unroll
            for (int r = 0; r < 4; r++) {
                const int row = m0 + wm + i * 16 + rb + r;
                if (row < M)
                    C[(size_t)row * 256 + col] =
                        __builtin_bit_cast(ushort, (__bf16)(acc[i][j][r] + bv));
            }
        }
    }
}

// ---------------------------------------------------------------------------
// Deformable bilinear sampling over BF16 val. One WAVE per (cam,q):
// 8 heads x 8 lanes, lane owns 4 channels (ushort4 = 8B gathers).
// ---------------------------------------------------------------------------
__global__ __launch_bounds__(256) void sample_kernel(const float* __restrict__ refp,
                                                     const float* __restrict__ offn,
                                                     const float* __restrict__ attnw,
                                                     const ushort* __restrict__ val,
                                                     const float* __restrict__ maskf,
                                                     float* __restrict__ out_cam) {
    const int wv = threadIdx.x >> 6, lane = threadIdx.x & 63;
    const int pair = blockIdx.x * 4 + wv;
    const int cam = pair >> 12, q = pair & (NQ - 1);
    if (maskf[cam * NQ + q] == 0.f) return;   // wave-uniform exit

    const int h = lane >> 3, dg = lane & 7;
    const float* refq = refp + ((size_t)cam * NQ + q) * 8;
    const float* offq = offn + (size_t)q * 512 + h * 64;
    const float* attq = attnw + (size_t)q * 256 + h * 32;
    const ushort* valc = val + (size_t)cam * LTOT * EMBED + h * HEAD_DIM + dg * 4;

    float rx[4], ry[4];
    #pragma unroll
    for (int i = 0; i < 4; i++) { rx[i] = refq[2 * i]; ry[i] = refq[2 * i + 1]; }

    const int Hs[4] = {92, 46, 23, 12};
    const int Ws[4] = {160, 80, 40, 20};
    const int st[4] = {0, 14720, 18400, 19320};

    float a0 = 0.f, a1 = 0.f, a2 = 0.f, a3 = 0.f;
    #pragma unroll
    for (int l = 0; l < LEVELS; l++) {
        const int H = Hs[l], W = Ws[l];
        const float fW = (float)W, fH = (float)H;
        const ushort* vl = valc + (size_t)st[l] * EMBED;
        #pragma unroll
        for (int p = 0; p < POINTS; p++) {
            const float x = (rx[p & 3] + offq[l * 16 + p * 2]) * fW - 0.5f;
            const float y = (ry[p & 3] + offq[l * 16 + p * 2 + 1]) * fH - 0.5f;
            const float x0f = floorf(x), y0f = floorf(y);
            const float lx = x - x0f, ly = y - y0f;
            const int x0 = (int)x0f, y0 = (int)y0f, x1 = x0 + 1, y1 = y0 + 1;
            const float aw = attq[l * 8 + p];
            const float w00 = (1.f - lx) * (1.f - ly) * aw;
            const float w10 = lx * (1.f - ly) * aw;
            const float w01 = (1.f - lx) * ly * aw;
            const float w11 = lx * ly * aw;
            const bool vx0 = (x0 >= 0) & (x0 < W), vx1 = (x1 >= 0) & (x1 < W);
            const bool vy0 = (y0 >= 0) & (y0 < H), vy1 = (y1 >= 0) & (y1 < H);
            if (vx0 & vy0) { const ushort4 v = *(const ushort4*)&vl[(size_t)(y0 * W + x0) * EMBED];
                a0 += w00 * bf2f(v.x); a1 += w00 * bf2f(v.y); a2 += w00 * bf2f(v.z); a3 += w00 * bf2f(v.w); }
            if (vx1 & vy0) { const ushort4 v = *(const ushort4*)&vl[(size_t)(y0 * W + x1) * EMBED];
                a0 += w10 * bf2f(v.x); a1 += w10 * bf2f(v.y); a2 += w10 * bf2f(v.z); a3 += w10 * bf2f(v.w); }
            if (vx0 & vy1) { const ushort4 v = *(const ushort4*)&vl[(size_t)(y1 * W + x0) * EMBED];
                a0 += w01 * bf2f(v.x); a1 += w01 * bf2f(v.y); a2 += w01 * bf2f(v.z); a3 += w01 * bf2f(v.w); }
            if (vx1 & vy1) { const ushort4 v = *(const ushort4*)&vl[(size_t)(y1 * W + x1) * EMBED];
                a0 += w11 * bf2f(v.x); a1 += w11 * bf2f(v.y); a2 += w11 * bf2f(v.z); a3 += w11 * bf2f(v.w); }
        }
    }
    float4 o; o.x = a0; o.y = a1; o.z = a2; o.w = a3;
    *(float4*)&out_cam[((size_t)cam * NQ + q) * EMBED + h * HEAD_DIM + dg * 4] = o;
}

// ---------------------------------------------------------------------------
// Masked mean over cams + output projection + residual.
// ---------------------------------------------------------------------------
__global__ __launch_bounds__(256) void out_kernel(const float* __restrict__ out_cam,
                                                  const float* __restrict__ maskf,
                                                  const float* __restrict__ countf,
                                                  const float* __restrict__ W_out,
                                                  const float* __restrict__ b_out,
                                                  const float* __restrict__ query,
                                                  float* __restrict__ out) {
    const int q = blockIdx.x;
    const int t = threadIdx.x;
    __shared__ float s[EMBED];
    float acc = 0.f;
    #pragma unroll
    for (int c = 0; c < CAMS; c++)
        acc += maskf[c * NQ + q] * out_cam[(((size_t)c * NQ + q) << 8) + t];
    s[t] = acc / countf[q];
    __syncthreads();
    float o = b_out[t];
    #pragma unroll 4
    for (int k = 0; k < EMBED; k++) o += s[k] * W_out[k * EMBED + t];
    out[(size_t)q * EMBED + t] = o + query[(size_t)q * EMBED + t];
}

extern "C" void kernel_launch(void* const* d_in, const int* in_sizes, int n_in,
                              void* d_out, int out_size, void* d_ws, size_t ws_size,
                              hipStream_t stream) {
    const float* query      = (const float*)d_in[0];
    const float* value_feat = (const float*)d_in[2];
    const float* refp       = (const float*)d_in[3];
    const void*  bev        = d_in[4];
    const float* W_value    = (const float*)d_in[7];
    const float* b_value    = (const float*)d_in[8];
    const float* W_off      = (const float*)d_in[9];
    const float* b_off      = (const float*)d_in[10];
    const float* W_attn     = (const float*)d_in[11];
    const float* b_attn     = (const float*)d_in[12];
    const float* W_out      = (const float*)d_in[13];
    const float* b_out      = (const float*)d_in[14];

    float* ws      = (float*)d_ws;
    float* offn    = ws;                             // 4096*512
    float* attnw   = offn + 2097152;                 // 4096*256
    float* maskf   = attnw + 1048576;                // 6*4096
    float* countf  = maskf + 24576;                  // 4096
    unsigned int* flag = (unsigned int*)(countf + 4096);
    ushort* val    = (ushort*)(countf + 4096 + 64);  // bf16: 117360*256 ushorts
    float* out_cam = (float*)(val + (size_t)MROWS * EMBED);  // 6*4096*256 f32
    ushort* WT     = (ushort*)(out_cam + (size_t)CAMS * NQ * EMBED);  // 64K ushorts

    detect_kernel<<<1, 256, 0, stream>>>((const unsigned int*)bev, flag);
    mask_kernel<<<16, 256, 0, stream>>>(bev, flag, maskf, countf);
    proj_kernel<<<NQ / 4, 256, 0, stream>>>(query, W_off, b_off, W_attn, b_attn, offn, attnw);
    wt_kernel<<<64, 256, 0, stream>>>(W_value, WT);
    gemm_mfma<<<dim3((MROWS + GBM - 1) / GBM, EMBED / GBN), 256, 0, stream>>>(
        value_feat, WT, b_value, val, MROWS);
    sample_kernel<<<CAMS * NQ / 4, 256, 0, stream>>>(refp, offn, attnw, val, maskf, out_cam);
    out_kernel<<<NQ, 256, 0, stream>>>(out_cam, maskf, countf, W_out, b_out, query, (float*)d_out);
}

// Round 5
// 310.815 us; speedup vs baseline: 2.6096x; 1.0876x over previous
//
#include <hip/hip_runtime.h>
#include <hip/hip_bf16.h>

#define NQ 4096
#define EMBED 256
#define HEADS 8
#define HEAD_DIM 32
#define LEVELS 4
#define POINTS 8
#define CAMS 6
#define LTOT 19560
#define MROWS (CAMS * LTOT)   // 117360

using bf16x8 = __attribute__((ext_vector_type(8))) __bf16;
using f32x4v = __attribute__((ext_vector_type(4))) float;

__device__ inline ushort f2bf(float f) {
    unsigned u = __builtin_bit_cast(unsigned, f);
    u += 0x7FFFu + ((u >> 16) & 1u);   // round-to-nearest-even
    return (ushort)(u >> 16);
}
__device__ inline float bf2f(ushort u) {
    return __builtin_bit_cast(float, ((unsigned)u) << 16);
}

// ---------------------------------------------------------------------------
// Detect bev_mask element size (uint8 bools vs int32).
// ---------------------------------------------------------------------------
__global__ __launch_bounds__(256) void detect_kernel(const unsigned int* __restrict__ bm,
                                                     unsigned int* __restrict__ flag) {
    __shared__ unsigned int red[256];
    const int t = threadIdx.x;
    unsigned int acc = 0;
    for (int i = t; i < (CAMS * NQ * 4) / 4; i += 256)
        acc |= (bm[i] & 0xFFFFFF00u);
    red[t] = acc;
    __syncthreads();
    for (int s = 128; s > 0; s >>= 1) {
        if (t < s) red[t] |= red[t + s];
        __syncthreads();
    }
    if (t == 0) flag[0] = red[0] ? 1u : 0u;
}

__global__ __launch_bounds__(256) void mask_kernel(const void* __restrict__ bm,
                                                   const unsigned int* __restrict__ flag,
                                                   float* __restrict__ maskf,
                                                   float* __restrict__ countf) {
    const int q = blockIdx.x * 256 + threadIdx.x;
    if (q >= NQ) return;
    const bool u8 = (flag[0] != 0);
    float cnt = 0.f;
    #pragma unroll
    for (int c = 0; c < CAMS; c++) {
        bool hit;
        if (u8) {
            const unsigned int w = ((const unsigned int*)bm)[c * NQ + q];
            hit = (w != 0);
        } else {
            const int* p = (const int*)bm;
            int s = 0;
            #pragma unroll
            for (int d = 0; d < 4; d++) s |= p[(c * NQ + q) * 4 + d];
            hit = (s != 0);
        }
        maskf[c * NQ + q] = hit ? 1.f : 0.f;
        cnt += hit ? 1.f : 0.f;
    }
    countf[q] = fmaxf(cnt, 1.f);
}

// ---------------------------------------------------------------------------
// Offset + attention projections + softmax (shared across cams).
// ---------------------------------------------------------------------------
__global__ __launch_bounds__(256) void proj_kernel(const float* __restrict__ query,
                                                   const float* __restrict__ W_off,
                                                   const float* __restrict__ b_off,
                                                   const float* __restrict__ W_attn,
                                                   const float* __restrict__ b_attn,
                                                   float* __restrict__ offn,
                                                   float* __restrict__ attnw) {
    const int t = threadIdx.x;
    const int q0 = blockIdx.x * 4;
    __shared__ float qs[4][EMBED];
    __shared__ float lat[4][EMBED];
    #pragma unroll
    for (int i = 0; i < 4; i++) qs[i][t] = query[(size_t)(q0 + i) * EMBED + t];
    __syncthreads();

    float aO0[4] = {0, 0, 0, 0}, aO1[4] = {0, 0, 0, 0}, aA[4] = {0, 0, 0, 0};
    #pragma unroll 4
    for (int k = 0; k < EMBED; k++) {
        const float w0 = W_off[k * 512 + t];
        const float w1 = W_off[k * 512 + 256 + t];
        const float wa = W_attn[k * 256 + t];
        #pragma unroll
        for (int i = 0; i < 4; i++) {
            const float qv = qs[i][k];
            aO0[i] += qv * w0;
            aO1[i] += qv * w1;
            aA[i]  += qv * wa;
        }
    }

    const float Wl[4] = {160.f, 80.f, 40.f, 20.f};
    const float Hl[4] = {92.f, 46.f, 23.f, 12.f};
    const int j0 = t, j1 = t + 256;
    const int l0 = (j0 & 63) >> 4, l1 = (j1 & 63) >> 4;
    const float inv0 = 1.0f / ((j0 & 1) ? Hl[l0] : Wl[l0]);
    const float inv1 = 1.0f / ((j1 & 1) ? Hl[l1] : Wl[l1]);
    const float bo0 = b_off[j0], bo1 = b_off[j1], ba = b_attn[t];
    #pragma unroll
    for (int i = 0; i < 4; i++) {
        offn[(size_t)(q0 + i) * 512 + j0] = (aO0[i] + bo0) * inv0;
        offn[(size_t)(q0 + i) * 512 + j1] = (aO1[i] + bo1) * inv1;
        lat[i][t] = aA[i] + ba;
    }
    __syncthreads();

    const int h = t >> 5, lane = t & 31;
    #pragma unroll
    for (int i = 0; i < 4; i++) {
        const float v = lat[i][h * 32 + lane];
        float m = v;
        for (int s = 16; s > 0; s >>= 1) m = fmaxf(m, __shfl_xor(m, s, 32));
        const float e = expf(v - m);
        float ssum = e;
        for (int s = 16; s > 0; s >>= 1) ssum += __shfl_xor(ssum, s, 32);
        attnw[(size_t)(q0 + i) * 256 + h * 32 + lane] = e / ssum;
    }
}

// ---------------------------------------------------------------------------
// W_value -> WT bf16 transposed [n][k] (one-time, tiny).
// ---------------------------------------------------------------------------
__global__ __launch_bounds__(256) void wt_kernel(const float* __restrict__ W,
                                                 ushort* __restrict__ WT) {
    __shared__ float tile[32][33];
    const int b = blockIdx.x;            // 64 blocks: 8x8 tiles of 32x32
    const int kt = b >> 3, nt = b & 7;
    const int t = threadIdx.x;
    const int r = t >> 5, c = t & 31;
    #pragma unroll
    for (int it = 0; it < 4; it++)
        tile[it * 8 + r][c] = W[(size_t)(kt * 32 + it * 8 + r) * 256 + nt * 32 + c];
    __syncthreads();
    #pragma unroll
    for (int it = 0; it < 4; it++)
        WT[(size_t)(nt * 32 + it * 8 + r) * 256 + kt * 32 + c] = f2bf(tile[c][it * 8 + r]);
}

// ---------------------------------------------------------------------------
// Value projection: bf16 MFMA GEMM, writes val in BF16.
// 128x128 tile, BK=32, 4 waves (2x2 of 64x64).
// ---------------------------------------------------------------------------
#define GBM 128
#define GBN 128
#define GBK 32
#define LDT 40   // padded LDS stride (bf16): 80 B, 16B-aligned, ~2-way banks

__global__ __launch_bounds__(256) void gemm_mfma(const float* __restrict__ A,
                                                 const ushort* __restrict__ WT,
                                                 const float* __restrict__ bias,
                                                 ushort* __restrict__ C, int M) {
    __shared__ ushort As[GBM * LDT];
    __shared__ ushort Bs[GBN * LDT];
    const int t = threadIdx.x;
    const int wave = t >> 6, lane = t & 63;
    const int wm = (wave & 1) * 64, wn = (wave >> 1) * 64;
    const int m0 = blockIdx.x * GBM, n0 = blockIdx.y * GBN;
    const int fl = lane & 15, fk = (lane >> 4) * 8;
    const int sr = t >> 1, sk = (t & 1) * 16;

    int ar = m0 + sr; if (ar >= M) ar = M - 1;
    const float*  arow = A  + (size_t)ar * 256;
    const ushort* brow = WT + (size_t)(n0 + sr) * 256;

    f32x4v acc[4][4];
    #pragma unroll
    for (int i = 0; i < 4; i++)
        #pragma unroll
        for (int j = 0; j < 4; j++) acc[i][j] = (f32x4v)(0.f);

    for (int k0 = 0; k0 < 256; k0 += GBK) {
        bf16x8 w0, w1;
        #pragma unroll
        for (int u = 0; u < 2; u++) {
            const float4 v = *(const float4*)&arow[k0 + sk + u * 4];
            w0[u * 4 + 0] = (__bf16)v.x; w0[u * 4 + 1] = (__bf16)v.y;
            w0[u * 4 + 2] = (__bf16)v.z; w0[u * 4 + 3] = (__bf16)v.w;
        }
        #pragma unroll
        for (int u = 0; u < 2; u++) {
            const float4 v = *(const float4*)&arow[k0 + sk + 8 + u * 4];
            w1[u * 4 + 0] = (__bf16)v.x; w1[u * 4 + 1] = (__bf16)v.y;
            w1[u * 4 + 2] = (__bf16)v.z; w1[u * 4 + 3] = (__bf16)v.w;
        }
        *(bf16x8*)&As[sr * LDT + sk]     = w0;
        *(bf16x8*)&As[sr * LDT + sk + 8] = w1;
        const uint4* bp = (const uint4*)&brow[k0 + sk];
        *(uint4*)&Bs[sr * LDT + sk]     = bp[0];
        *(uint4*)&Bs[sr * LDT + sk + 8] = bp[1];
        __syncthreads();

        bf16x8 af[4], bfv[4];
        #pragma unroll
        for (int i = 0; i < 4; i++)
            af[i] = *(const bf16x8*)&As[(wm + i * 16 + fl) * LDT + fk];
        #pragma unroll
        for (int j = 0; j < 4; j++)
            bfv[j] = *(const bf16x8*)&Bs[(wn + j * 16 + fl) * LDT + fk];
        #pragma unroll
        for (int i = 0; i < 4; i++)
            #pragma unroll
            for (int j = 0; j < 4; j++)
                acc[i][j] = __builtin_amdgcn_mfma_f32_16x16x32_bf16(af[i], bfv[j], acc[i][j], 0, 0, 0);
        __syncthreads();
    }

    const int rb = (lane >> 4) * 4;
    #pragma unroll
    for (int j = 0; j < 4; j++) {
        const int col = n0 + wn + j * 16 + fl;
        const float bv = bias[col];
        #pragma unroll
        for (int i = 0; i < 4; i++) {
            #pragma unroll
            for (int r = 0; r < 4; r++) {
                const int row = m0 + wm + i * 16 + rb + r;
                if (row < M)
                    C[(size_t)row * 256 + col] =
                        __builtin_bit_cast(ushort, (__bf16)(acc[i][j][r] + bv));
            }
        }
    }
}

// ---------------------------------------------------------------------------
// Deformable bilinear sampling over BF16 val. One WAVE per (cam,q):
// 8 heads x 8 lanes, lane owns 4 channels (ushort4 = 8B gathers).
// Branchless corner handling + 16-deep batched load pipeline (4 points x
// 4 corners issued before any accumulation) to expose memory parallelism.
// ---------------------------------------------------------------------------
__global__ __launch_bounds__(256) void sample_kernel(const float* __restrict__ refp,
                                                     const float* __restrict__ offn,
                                                     const float* __restrict__ attnw,
                                                     const ushort* __restrict__ val,
                                                     const float* __restrict__ maskf,
                                                     float* __restrict__ out_cam) {
    const int wv = threadIdx.x >> 6, lane = threadIdx.x & 63;
    const int pair = blockIdx.x * 4 + wv;
    const int cam = pair >> 12, q = pair & (NQ - 1);
    if (maskf[cam * NQ + q] == 0.f) return;   // wave-uniform exit

    const int h = lane >> 3, dg = lane & 7;
    const float* refq = refp + ((size_t)cam * NQ + q) * 8;
    const float* offq = offn + (size_t)q * 512 + h * 64;
    const float* attq = attnw + (size_t)q * 256 + h * 32;
    const ushort* valc = val + (size_t)cam * LTOT * EMBED + h * HEAD_DIM + dg * 4;

    float rx[4], ry[4];
    #pragma unroll
    for (int i = 0; i < 4; i++) { rx[i] = refq[2 * i]; ry[i] = refq[2 * i + 1]; }

    const int Hs[4] = {92, 46, 23, 12};
    const int Ws[4] = {160, 80, 40, 20};
    const int st[4] = {0, 14720, 18400, 19320};

    float a0 = 0.f, a1 = 0.f, a2 = 0.f, a3 = 0.f;
    #pragma unroll
    for (int l = 0; l < LEVELS; l++) {
        const int H = Hs[l], W = Ws[l];
        const float fW = (float)W, fH = (float)H;
        const ushort* vl = valc + (size_t)st[l] * EMBED;
        #pragma unroll
        for (int pg = 0; pg < 2; pg++) {
            float wts[16];
            ushort4 vv[16];
            #pragma unroll
            for (int pp = 0; pp < 4; pp++) {
                const int p = pg * 4 + pp;
                const float x = (rx[p & 3] + offq[l * 16 + p * 2]) * fW - 0.5f;
                const float y = (ry[p & 3] + offq[l * 16 + p * 2 + 1]) * fH - 0.5f;
                const float x0f = floorf(x), y0f = floorf(y);
                const float lx = x - x0f, ly = y - y0f;
                const int x0 = (int)x0f, y0 = (int)y0f, x1 = x0 + 1, y1 = y0 + 1;
                const float aw = attq[l * 8 + p];
                // validity folded into weights (branchless)
                const float vx0 = (x0 >= 0 && x0 < W) ? 1.f : 0.f;
                const float vx1 = (x1 >= 0 && x1 < W) ? 1.f : 0.f;
                const float vy0 = (y0 >= 0 && y0 < H) ? 1.f : 0.f;
                const float vy1 = (y1 >= 0 && y1 < H) ? 1.f : 0.f;
                wts[pp * 4 + 0] = (1.f - lx) * (1.f - ly) * aw * vx0 * vy0;
                wts[pp * 4 + 1] = lx * (1.f - ly) * aw * vx1 * vy0;
                wts[pp * 4 + 2] = (1.f - lx) * ly * aw * vx0 * vy1;
                wts[pp * 4 + 3] = lx * ly * aw * vx1 * vy1;
                // clamped addresses, unconditional loads
                const int cx0 = min(max(x0, 0), W - 1), cx1 = min(max(x1, 0), W - 1);
                const int cy0 = min(max(y0, 0), H - 1), cy1 = min(max(y1, 0), H - 1);
                vv[pp * 4 + 0] = *(const ushort4*)&vl[(size_t)(cy0 * W + cx0) * EMBED];
                vv[pp * 4 + 1] = *(const ushort4*)&vl[(size_t)(cy0 * W + cx1) * EMBED];
                vv[pp * 4 + 2] = *(const ushort4*)&vl[(size_t)(cy1 * W + cx0) * EMBED];
                vv[pp * 4 + 3] = *(const ushort4*)&vl[(size_t)(cy1 * W + cx1) * EMBED];
            }
            #pragma unroll
            for (int c2 = 0; c2 < 16; c2++) {
                const float w = wts[c2];
                a0 += w * bf2f(vv[c2].x);
                a1 += w * bf2f(vv[c2].y);
                a2 += w * bf2f(vv[c2].z);
                a3 += w * bf2f(vv[c2].w);
            }
        }
    }
    float4 o; o.x = a0; o.y = a1; o.z = a2; o.w = a3;
    *(float4*)&out_cam[((size_t)cam * NQ + q) * EMBED + h * HEAD_DIM + dg * 4] = o;
}

// ---------------------------------------------------------------------------
// Masked mean over cams + output projection + residual.
// ---------------------------------------------------------------------------
__global__ __launch_bounds__(256) void out_kernel(const float* __restrict__ out_cam,
                                                  const float* __restrict__ maskf,
                                                  const float* __restrict__ countf,
                                                  const float* __restrict__ W_out,
                                                  const float* __restrict__ b_out,
                                                  const float* __restrict__ query,
                                                  float* __restrict__ out) {
    const int q = blockIdx.x;
    const int t = threadIdx.x;
    __shared__ float s[EMBED];
    float acc = 0.f;
    #pragma unroll
    for (int c = 0; c < CAMS; c++)
        acc += maskf[c * NQ + q] * out_cam[(((size_t)c * NQ + q) << 8) + t];
    s[t] = acc / countf[q];
    __syncthreads();
    float o = b_out[t];
    #pragma unroll 4
    for (int k = 0; k < EMBED; k++) o += s[k] * W_out[k * EMBED + t];
    out[(size_t)q * EMBED + t] = o + query[(size_t)q * EMBED + t];
}

extern "C" void kernel_launch(void* const* d_in, const int* in_sizes, int n_in,
                              void* d_out, int out_size, void* d_ws, size_t ws_size,
                              hipStream_t stream) {
    const float* query      = (const float*)d_in[0];
    const float* value_feat = (const float*)d_in[2];
    const float* refp       = (const float*)d_in[3];
    const void*  bev        = d_in[4];
    const float* W_value    = (const float*)d_in[7];
    const float* b_value    = (const float*)d_in[8];
    const float* W_off      = (const float*)d_in[9];
    const float* b_off      = (const float*)d_in[10];
    const float* W_attn     = (const float*)d_in[11];
    const float* b_attn     = (const float*)d_in[12];
    const float* W_out      = (const float*)d_in[13];
    const float* b_out      = (const float*)d_in[14];

    float* ws      = (float*)d_ws;
    float* offn    = ws;                             // 4096*512
    float* attnw   = offn + 2097152;                 // 4096*256
    float* maskf   = attnw + 1048576;                // 6*4096
    float* countf  = maskf + 24576;                  // 4096
    unsigned int* flag = (unsigned int*)(countf + 4096);
    ushort* val    = (ushort*)(countf + 4096 + 64);  // bf16: 117360*256 ushorts
    float* out_cam = (float*)(val + (size_t)MROWS * EMBED);  // 6*4096*256 f32
    ushort* WT     = (ushort*)(out_cam + (size_t)CAMS * NQ * EMBED);  // 64K ushorts

    detect_kernel<<<1, 256, 0, stream>>>((const unsigned int*)bev, flag);
    mask_kernel<<<16, 256, 0, stream>>>(bev, flag, maskf, countf);
    proj_kernel<<<NQ / 4, 256, 0, stream>>>(query, W_off, b_off, W_attn, b_attn, offn, attnw);
    wt_kernel<<<64, 256, 0, stream>>>(W_value, WT);
    gemm_mfma<<<dim3((MROWS + GBM - 1) / GBM, EMBED / GBN), 256, 0, stream>>>(
        value_feat, WT, b_value, val, MROWS);
    sample_kernel<<<CAMS * NQ / 4, 256, 0, stream>>>(refp, offn, attnw, val, maskf, out_cam);
    out_kernel<<<NQ, 256, 0, stream>>>(out_cam, maskf, countf, W_out, b_out, query, (float*)d_out);
}